// Round 1
// baseline (895.296 us; speedup 1.0000x reference)
//
#include <hip/hip_runtime.h>

#define N_NODES   50000
#define N_EDGES   800000
#define N_FEAT    128
#define HIDDEN    64
#define N_LAYERS  3
#define N_GRAPHS  512
#define N_CLASSES 10
#define BN_EPS    1e-5f

// ---------------- encoder: h = x @ enc_w + enc_b  ([50000,128]@[128,64]) ---
__global__ __launch_bounds__(256) void enc_kernel(
    const float* __restrict__ x, const float* __restrict__ w,
    const float* __restrict__ b, float* __restrict__ h)
{
    __shared__ float wl[N_FEAT * HIDDEN];   // 32 KB weights
    __shared__ float xs[4 * N_FEAT];        // 2 KB: 4 staged input rows
    for (int i = threadIdx.x; i < N_FEAT * HIDDEN; i += 256)
        wl[i] = w[i];
    const int col = threadIdx.x & 63;
    const int row = threadIdx.x >> 6;       // 0..3
    const float bias = b[col];
    for (int base = blockIdx.x * 4; base < N_NODES; base += gridDim.x * 4) {
        __syncthreads();   // covers wl load on iter 0, xs reuse afterwards
        for (int i = threadIdx.x; i < 4 * N_FEAT; i += 256) {
            int nn = base + (i >> 7);
            xs[i] = (nn < N_NODES) ? x[(size_t)nn * N_FEAT + (i & 127)] : 0.0f;
        }
        __syncthreads();
        int node = base + row;
        if (node < N_NODES) {
            float acc = bias;
            for (int k = 0; k < N_FEAT; ++k)
                acc = fmaf(xs[row * N_FEAT + k], wl[k * HIDDEN + col], acc);
            h[(size_t)node * HIDDEN + col] = acc;
        }
    }
}

// ---------------- z = (1+eps[l]) * h ---------------------------------------
__global__ void scale_kernel(const float* __restrict__ h, float* __restrict__ z,
                             const float* __restrict__ eps, int layer)
{
    float f = 1.0f + eps[layer];
    size_t n = (size_t)N_NODES * HIDDEN;
    for (size_t i = (size_t)blockIdx.x * blockDim.x + threadIdx.x; i < n;
         i += (size_t)gridDim.x * blockDim.x)
        z[i] = f * h[i];
}

// ---------------- z[dst] += h[src] over edges (atomic scatter) -------------
__global__ __launch_bounds__(256) void scatter_kernel(
    const float* __restrict__ h, const int* __restrict__ ei, float* __restrict__ z)
{
    size_t gid = (size_t)blockIdx.x * 256 + threadIdx.x;
    if (gid >= (size_t)N_EDGES * HIDDEN) return;
    int e = (int)(gid >> 6);
    int c = (int)(gid & 63);
    int s = ei[e];
    int d = ei[N_EDGES + e];
    atomicAdd(&z[(size_t)d * HIDDEN + c], h[(size_t)s * HIDDEN + c]);
}

// ---------------- per-node [64]@[64,64] MLP step, optional relu / BN stats -
// in and out may alias (row is staged through LDS before the store).
template<bool RELU, bool STATS>
__global__ __launch_bounds__(256) void mlp_kernel(
    const float* in, const float* __restrict__ w,
    const float* __restrict__ b, float* out, float* __restrict__ stats)
{
    __shared__ float wl[HIDDEN * HIDDEN];   // 16 KB
    __shared__ float xs[4 * HIDDEN];        // 1 KB
    __shared__ float red[512];
    for (int i = threadIdx.x; i < HIDDEN * HIDDEN; i += 256)
        wl[i] = w[i];
    const int col = threadIdx.x & 63;
    const int row = threadIdx.x >> 6;
    const float bias = b[col];
    float s = 0.f, s2 = 0.f;
    for (int base = blockIdx.x * 4; base < N_NODES; base += gridDim.x * 4) {
        __syncthreads();
        int node = base + row;
        if (node < N_NODES) xs[threadIdx.x] = in[(size_t)node * HIDDEN + col];
        __syncthreads();
        if (node < N_NODES) {
            float acc = bias;
            for (int k = 0; k < HIDDEN; ++k)
                acc = fmaf(xs[row * HIDDEN + k], wl[k * HIDDEN + col], acc);
            if (RELU) acc = fmaxf(acc, 0.f);
            out[(size_t)node * HIDDEN + col] = acc;
            if (STATS) { s += acc; s2 += acc * acc; }
        }
    }
    if (STATS) {
        __syncthreads();
        red[threadIdx.x] = s;
        red[256 + threadIdx.x] = s2;
        __syncthreads();
        if (row == 0) {
            float ts  = red[col] + red[64 + col] + red[128 + col] + red[192 + col];
            float ts2 = red[256 + col] + red[320 + col] + red[384 + col] + red[448 + col];
            atomicAdd(&stats[col], ts);
            atomicAdd(&stats[HIDDEN + col], ts2);
        }
    }
}

// ---------------- batchnorm (batch stats) + relu, in place -----------------
__global__ void bn_relu_kernel(float* __restrict__ zh, const float* __restrict__ stats,
                               const float* __restrict__ gamma, const float* __restrict__ beta)
{
    const float invN = 1.0f / (float)N_NODES;
    size_t n = (size_t)N_NODES * HIDDEN;
    for (size_t i = (size_t)blockIdx.x * blockDim.x + threadIdx.x; i < n;
         i += (size_t)gridDim.x * blockDim.x) {
        int col = (int)(i & 63);
        float mean = stats[col] * invN;
        float var  = stats[HIDDEN + col] * invN - mean * mean;
        float inv  = rsqrtf(fmaxf(var, 0.f) + BN_EPS);
        float v = (zh[i] - mean) * inv * gamma[col] + beta[col];
        zh[i] = fmaxf(v, 0.f);
    }
}

// ---------------- mean pool per graph (atomic scatter) ---------------------
__global__ __launch_bounds__(256) void pool_kernel(
    const float* __restrict__ h, const int* __restrict__ batch,
    float* __restrict__ pooled, float* __restrict__ counts)
{
    size_t gid = (size_t)blockIdx.x * 256 + threadIdx.x;
    if (gid >= (size_t)N_NODES * HIDDEN) return;
    int node = (int)(gid >> 6);
    int c = (int)(gid & 63);
    int g = batch[node];
    atomicAdd(&pooled[(size_t)g * HIDDEN + c], h[gid]);
    if (c == 0) atomicAdd(&counts[g], 1.0f);
}

// ---------------- out = (pooled/count) @ lin_w + lin_b ---------------------
__global__ void out_kernel(const float* __restrict__ pooled, const float* __restrict__ counts,
                           const float* __restrict__ w, const float* __restrict__ b,
                           float* __restrict__ out)
{
    int gid = blockIdx.x * blockDim.x + threadIdx.x;
    if (gid >= N_GRAPHS * N_CLASSES) return;
    int g = gid / N_CLASSES;
    int c = gid - g * N_CLASSES;
    float inv = 1.0f / fmaxf(counts[g], 1.0f);
    float acc = b[c];
    for (int j = 0; j < HIDDEN; ++j)
        acc = fmaf(pooled[(size_t)g * HIDDEN + j] * inv, w[j * N_CLASSES + c], acc);
    out[gid] = acc;
}

extern "C" void kernel_launch(void* const* d_in, const int* in_sizes, int n_in,
                              void* d_out, int out_size, void* d_ws, size_t ws_size,
                              hipStream_t stream)
{
    const float* x       = (const float*)d_in[0];
    const int*   ei      = (const int*)d_in[1];   // [2, N_EDGES]: src then dst
    const int*   batch   = (const int*)d_in[2];
    const float* enc_w   = (const float*)d_in[3];
    const float* enc_b   = (const float*)d_in[4];
    const float* eps     = (const float*)d_in[5];
    const float* conv_w1 = (const float*)d_in[6];
    const float* conv_b1 = (const float*)d_in[7];
    const float* conv_w2 = (const float*)d_in[8];
    const float* conv_b2 = (const float*)d_in[9];
    const float* bn_g    = (const float*)d_in[10];
    const float* bn_b    = (const float*)d_in[11];
    const float* lin_w   = (const float*)d_in[12];
    const float* lin_b   = (const float*)d_in[13];
    float* out = (float*)d_out;

    char* ws = (char*)d_ws;
    const size_t HB = (size_t)N_NODES * HIDDEN * sizeof(float);  // 12.8 MB
    float* h      = (float*)(ws);
    float* z      = (float*)(ws + HB);
    float* stats  = (float*)(ws + 2 * HB);                 // 128 floats
    float* pooled = (float*)(ws + 2 * HB + 1024);          // 512*64 floats
    float* counts = (float*)(ws + 2 * HB + 1024 + (size_t)N_GRAPHS * HIDDEN * sizeof(float));

    enc_kernel<<<1024, 256, 0, stream>>>(x, enc_w, enc_b, h);

    for (int l = 0; l < N_LAYERS; ++l) {
        scale_kernel<<<2048, 256, 0, stream>>>(h, z, eps, l);
        scatter_kernel<<<(N_EDGES * HIDDEN) / 256, 256, 0, stream>>>(h, ei, z);
        hipMemsetAsync(stats, 0, 2 * HIDDEN * sizeof(float), stream);
        mlp_kernel<true,  false><<<1024, 256, 0, stream>>>(
            z, conv_w1 + (size_t)l * HIDDEN * HIDDEN, conv_b1 + (size_t)l * HIDDEN, z, nullptr);
        mlp_kernel<false, true ><<<1024, 256, 0, stream>>>(
            z, conv_w2 + (size_t)l * HIDDEN * HIDDEN, conv_b2 + (size_t)l * HIDDEN, h, stats);
        bn_relu_kernel<<<2048, 256, 0, stream>>>(h, stats, bn_g + (size_t)l * HIDDEN,
                                                 bn_b + (size_t)l * HIDDEN);
    }

    hipMemsetAsync(pooled, 0, (size_t)N_GRAPHS * HIDDEN * sizeof(float), stream);
    hipMemsetAsync(counts, 0, (size_t)N_GRAPHS * sizeof(float), stream);
    pool_kernel<<<((size_t)N_NODES * HIDDEN + 255) / 256, 256, 0, stream>>>(h, batch, pooled, counts);
    out_kernel<<<(N_GRAPHS * N_CLASSES + 255) / 256, 256, 0, stream>>>(pooled, counts, lin_w, lin_b, out);
}

// Round 2
// 701.924 us; speedup vs baseline: 1.2755x; 1.2755x over previous
//
#include <hip/hip_runtime.h>

#define N_NODES   50000
#define N_EDGES   800000
#define N_FEAT    128
#define HIDDEN    64
#define N_LAYERS  3
#define N_GRAPHS  512
#define N_CLASSES 10
#define BN_EPS    1e-5f

// ---------------- encoder: h = x @ enc_w + enc_b  ([50000,128]@[128,64]) ---
__global__ __launch_bounds__(256) void enc_kernel(
    const float* __restrict__ x, const float* __restrict__ w,
    const float* __restrict__ b, float* __restrict__ h)
{
    __shared__ float wl[N_FEAT * HIDDEN];   // 32 KB weights
    __shared__ float xs[4 * N_FEAT];        // 2 KB: 4 staged input rows
    for (int i = threadIdx.x; i < N_FEAT * HIDDEN; i += 256)
        wl[i] = w[i];
    const int col = threadIdx.x & 63;
    const int row = threadIdx.x >> 6;       // 0..3
    const float bias = b[col];
    for (int base = blockIdx.x * 4; base < N_NODES; base += gridDim.x * 4) {
        __syncthreads();   // covers wl load on iter 0, xs reuse afterwards
        for (int i = threadIdx.x; i < 4 * N_FEAT; i += 256) {
            int nn = base + (i >> 7);
            xs[i] = (nn < N_NODES) ? x[(size_t)nn * N_FEAT + (i & 127)] : 0.0f;
        }
        __syncthreads();
        int node = base + row;
        if (node < N_NODES) {
            float acc = bias;
            for (int k = 0; k < N_FEAT; ++k)
                acc = fmaf(xs[row * N_FEAT + k], wl[k * HIDDEN + col], acc);
            h[(size_t)node * HIDDEN + col] = acc;
        }
    }
}

// ---------------- CSR build: histogram of dst -------------------------------
__global__ __launch_bounds__(256) void hist_kernel(const int* __restrict__ ei,
                                                   int* __restrict__ deg)
{
    int e = blockIdx.x * 256 + threadIdx.x;
    if (e < N_EDGES) atomicAdd(&deg[ei[N_EDGES + e]], 1);
}

// ---------------- CSR build: single-block exclusive scan --------------------
// row_start[0..N_NODES], cursor = copy of row_start[0..N_NODES-1]
__global__ __launch_bounds__(1024) void scan_kernel(const int* __restrict__ deg,
                                                    int* __restrict__ row_start,
                                                    int* __restrict__ cursor)
{
    __shared__ int sums[1024];
    const int C = (N_NODES + 1023) / 1024;   // 49
    const int tid = threadIdx.x;
    const int base = tid * C;
    int local = 0;
    for (int i = base; i < base + C && i < N_NODES; ++i) local += deg[i];
    sums[tid] = local;
    __syncthreads();
    for (int off = 1; off < 1024; off <<= 1) {
        int v = (tid >= off) ? sums[tid - off] : 0;
        __syncthreads();
        if (tid >= off) sums[tid] += v;
        __syncthreads();
    }
    int run = (tid > 0) ? sums[tid - 1] : 0;   // exclusive prefix of this chunk
    for (int i = base; i < base + C && i < N_NODES; ++i) {
        row_start[i] = run;
        cursor[i]    = run;
        run += deg[i];
    }
    if (tid == 1023) row_start[N_NODES] = sums[1023];
}

// ---------------- CSR build: fill sorted src list ---------------------------
__global__ __launch_bounds__(256) void fill_kernel(const int* __restrict__ ei,
                                                   int* __restrict__ cursor,
                                                   int* __restrict__ csr_src)
{
    int e = blockIdx.x * 256 + threadIdx.x;
    if (e >= N_EDGES) return;
    int d = ei[N_EDGES + e];
    int pos = atomicAdd(&cursor[d], 1);
    csr_src[pos] = ei[e];
}

// ---------------- z = (1+eps)*h + sum_{src in CSR[node]} h[src] -------------
// one wave per node; col = lane
__global__ __launch_bounds__(256) void gather_kernel(
    const float* __restrict__ h, const int* __restrict__ csr_src,
    const int* __restrict__ row_start, float* __restrict__ z,
    const float* __restrict__ eps, int layer)
{
    const int col  = threadIdx.x & 63;
    const int wv   = threadIdx.x >> 6;
    const int node = blockIdx.x * 4 + wv;
    if (node >= N_NODES) return;
    const int s0 = row_start[node];
    const int s1 = row_start[node + 1];
    float acc = (1.0f + eps[layer]) * h[(size_t)node * HIDDEN + col];
    for (int j = s0; j < s1; ++j) {
        int s = csr_src[j];                       // wave-uniform
        acc += h[(size_t)s * HIDDEN + col];       // coalesced 256B row
    }
    z[(size_t)node * HIDDEN + col] = acc;
}

// ---------------- per-node [64]@[64,64] MLP step, optional relu / BN stats -
template<bool RELU, bool STATS>
__global__ __launch_bounds__(256) void mlp_kernel(
    const float* in, const float* __restrict__ w,
    const float* __restrict__ b, float* out, float* __restrict__ stats)
{
    __shared__ float wl[HIDDEN * HIDDEN];   // 16 KB
    __shared__ float xs[4 * HIDDEN];        // 1 KB
    __shared__ float red[512];
    for (int i = threadIdx.x; i < HIDDEN * HIDDEN; i += 256)
        wl[i] = w[i];
    const int col = threadIdx.x & 63;
    const int row = threadIdx.x >> 6;
    const float bias = b[col];
    float s = 0.f, s2 = 0.f;
    for (int base = blockIdx.x * 4; base < N_NODES; base += gridDim.x * 4) {
        __syncthreads();
        int node = base + row;
        if (node < N_NODES) xs[threadIdx.x] = in[(size_t)node * HIDDEN + col];
        __syncthreads();
        if (node < N_NODES) {
            float acc = bias;
            for (int k = 0; k < HIDDEN; ++k)
                acc = fmaf(xs[row * HIDDEN + k], wl[k * HIDDEN + col], acc);
            if (RELU) acc = fmaxf(acc, 0.f);
            out[(size_t)node * HIDDEN + col] = acc;
            if (STATS) { s += acc; s2 += acc * acc; }
        }
    }
    if (STATS) {
        __syncthreads();
        red[threadIdx.x] = s;
        red[256 + threadIdx.x] = s2;
        __syncthreads();
        if (row == 0) {
            float ts  = red[col] + red[64 + col] + red[128 + col] + red[192 + col];
            float ts2 = red[256 + col] + red[320 + col] + red[384 + col] + red[448 + col];
            atomicAdd(&stats[col], ts);
            atomicAdd(&stats[HIDDEN + col], ts2);
        }
    }
}

// ---------------- batchnorm (batch stats) + relu, in place -----------------
__global__ void bn_relu_kernel(float* __restrict__ zh, const float* __restrict__ stats,
                               const float* __restrict__ gamma, const float* __restrict__ beta)
{
    const float invN = 1.0f / (float)N_NODES;
    size_t n = (size_t)N_NODES * HIDDEN;
    for (size_t i = (size_t)blockIdx.x * blockDim.x + threadIdx.x; i < n;
         i += (size_t)gridDim.x * blockDim.x) {
        int col = (int)(i & 63);
        float mean = stats[col] * invN;
        float var  = stats[HIDDEN + col] * invN - mean * mean;
        float inv  = rsqrtf(fmaxf(var, 0.f) + BN_EPS);
        float v = (zh[i] - mean) * inv * gamma[col] + beta[col];
        zh[i] = fmaxf(v, 0.f);
    }
}

__device__ __forceinline__ int lbound(const int* __restrict__ a, int n, int v)
{
    int lo = 0, hi = n;
    while (lo < hi) { int m = (lo + hi) >> 1; if (a[m] < v) lo = m + 1; else hi = m; }
    return lo;
}

// ---------------- mean pool: one block per graph (batch is sorted) ---------
__global__ __launch_bounds__(256) void pool_kernel(
    const float* __restrict__ h, const int* __restrict__ batch,
    float* __restrict__ pooled)
{
    __shared__ int bounds[2];
    __shared__ float red[256];
    const int g = blockIdx.x;
    if (threadIdx.x < 2)
        bounds[threadIdx.x] = lbound(batch, N_NODES, g + threadIdx.x);
    __syncthreads();
    const int start = bounds[0], end = bounds[1];
    const int col = threadIdx.x & 63;
    const int row = threadIdx.x >> 6;
    float s = 0.f;
    for (int r = start + row; r < end; r += 4)
        s += h[(size_t)r * HIDDEN + col];
    red[threadIdx.x] = s;
    __syncthreads();
    if (row == 0) {
        float t = red[col] + red[64 + col] + red[128 + col] + red[192 + col];
        pooled[(size_t)g * HIDDEN + col] = t / fmaxf((float)(end - start), 1.0f);
    }
}

// ---------------- out = pooled @ lin_w + lin_b ------------------------------
__global__ void out_kernel(const float* __restrict__ pooled,
                           const float* __restrict__ w, const float* __restrict__ b,
                           float* __restrict__ out)
{
    int gid = blockIdx.x * blockDim.x + threadIdx.x;
    if (gid >= N_GRAPHS * N_CLASSES) return;
    int g = gid / N_CLASSES;
    int c = gid - g * N_CLASSES;
    float acc = b[c];
    for (int j = 0; j < HIDDEN; ++j)
        acc = fmaf(pooled[(size_t)g * HIDDEN + j], w[j * N_CLASSES + c], acc);
    out[gid] = acc;
}

extern "C" void kernel_launch(void* const* d_in, const int* in_sizes, int n_in,
                              void* d_out, int out_size, void* d_ws, size_t ws_size,
                              hipStream_t stream)
{
    const float* x       = (const float*)d_in[0];
    const int*   ei      = (const int*)d_in[1];   // [2, N_EDGES]: src then dst
    const int*   batch   = (const int*)d_in[2];
    const float* enc_w   = (const float*)d_in[3];
    const float* enc_b   = (const float*)d_in[4];
    const float* eps     = (const float*)d_in[5];
    const float* conv_w1 = (const float*)d_in[6];
    const float* conv_b1 = (const float*)d_in[7];
    const float* conv_w2 = (const float*)d_in[8];
    const float* conv_b2 = (const float*)d_in[9];
    const float* bn_g    = (const float*)d_in[10];
    const float* bn_b    = (const float*)d_in[11];
    const float* lin_w   = (const float*)d_in[12];
    const float* lin_b   = (const float*)d_in[13];
    float* out = (float*)d_out;

    char* ws = (char*)d_ws;
    const size_t HB = (size_t)N_NODES * HIDDEN * sizeof(float);  // 12.8 MB
    size_t off = 0;
    float* h      = (float*)(ws + off); off += HB;
    float* z      = (float*)(ws + off); off += HB;
    float* stats  = (float*)(ws + off); off += 1024;                       // 128 floats
    float* pooled = (float*)(ws + off); off += (size_t)N_GRAPHS * HIDDEN * sizeof(float);
    int* deg       = (int*)(ws + off); off += 50432 * sizeof(int);
    int* row_start = (int*)(ws + off); off += 50432 * sizeof(int);         // N_NODES+1
    int* cursor    = (int*)(ws + off); off += 50432 * sizeof(int);
    int* csr_src   = (int*)(ws + off); off += (size_t)N_EDGES * sizeof(int);

    // ---- CSR build (overlaps nothing; runs while encoder is queued) ----
    hipMemsetAsync(deg, 0, N_NODES * sizeof(int), stream);
    enc_kernel<<<1024, 256, 0, stream>>>(x, enc_w, enc_b, h);
    hist_kernel<<<(N_EDGES + 255) / 256, 256, 0, stream>>>(ei, deg);
    scan_kernel<<<1, 1024, 0, stream>>>(deg, row_start, cursor);
    fill_kernel<<<(N_EDGES + 255) / 256, 256, 0, stream>>>(ei, cursor, csr_src);

    for (int l = 0; l < N_LAYERS; ++l) {
        gather_kernel<<<(N_NODES + 3) / 4, 256, 0, stream>>>(h, csr_src, row_start, z, eps, l);
        hipMemsetAsync(stats, 0, 2 * HIDDEN * sizeof(float), stream);
        mlp_kernel<true,  false><<<1024, 256, 0, stream>>>(
            z, conv_w1 + (size_t)l * HIDDEN * HIDDEN, conv_b1 + (size_t)l * HIDDEN, z, nullptr);
        mlp_kernel<false, true ><<<1024, 256, 0, stream>>>(
            z, conv_w2 + (size_t)l * HIDDEN * HIDDEN, conv_b2 + (size_t)l * HIDDEN, h, stats);
        bn_relu_kernel<<<2048, 256, 0, stream>>>(h, stats, bn_g + (size_t)l * HIDDEN,
                                                 bn_b + (size_t)l * HIDDEN);
    }

    pool_kernel<<<N_GRAPHS, 256, 0, stream>>>(h, batch, pooled);
    out_kernel<<<(N_GRAPHS * N_CLASSES + 255) / 256, 256, 0, stream>>>(pooled, lin_w, lin_b, out);
}

// Round 3
// 605.777 us; speedup vs baseline: 1.4779x; 1.1587x over previous
//
#include <hip/hip_runtime.h>

#define N_NODES   50000
#define N_EDGES   800000
#define N_FEAT    128
#define HIDDEN    64
#define N_LAYERS  3
#define N_GRAPHS  512
#define N_CLASSES 10
#define BN_EPS    1e-5f
#define SCAN_BLK  196   // ceil(N_NODES/256)

// ---------------- encoder: h = x @ enc_w + enc_b  ([50000,128]@[128,64]) ---
__global__ __launch_bounds__(256) void enc_kernel(
    const float* __restrict__ x, const float* __restrict__ w,
    const float* __restrict__ b, float* __restrict__ h)
{
    __shared__ float wl[N_FEAT * HIDDEN];   // 32 KB weights
    __shared__ float xs[4 * N_FEAT];        // 2 KB: 4 staged input rows
    for (int i = threadIdx.x; i < N_FEAT * HIDDEN; i += 256)
        wl[i] = w[i];
    const int col = threadIdx.x & 63;
    const int row = threadIdx.x >> 6;       // 0..3
    const float bias = b[col];
    for (int base = blockIdx.x * 4; base < N_NODES; base += gridDim.x * 4) {
        __syncthreads();
        for (int i = threadIdx.x; i < 4 * N_FEAT; i += 256) {
            int nn = base + (i >> 7);
            xs[i] = (nn < N_NODES) ? x[(size_t)nn * N_FEAT + (i & 127)] : 0.0f;
        }
        __syncthreads();
        int node = base + row;
        if (node < N_NODES) {
            float acc = bias;
            for (int k = 0; k < N_FEAT; ++k)
                acc = fmaf(xs[row * N_FEAT + k], wl[k * HIDDEN + col], acc);
            h[(size_t)node * HIDDEN + col] = acc;
        }
    }
}

// ---------------- CSR build ------------------------------------------------
__global__ __launch_bounds__(256) void hist_kernel(const int* __restrict__ ei,
                                                   int* __restrict__ deg)
{
    int e = blockIdx.x * 256 + threadIdx.x;
    if (e < N_EDGES) atomicAdd(&deg[ei[N_EDGES + e]], 1);
}

// stage 1: per-256-chunk exclusive scan into row_start, chunk totals to bsum
__global__ __launch_bounds__(256) void scan1_kernel(const int* __restrict__ deg,
                                                    int* __restrict__ row_start,
                                                    int* __restrict__ bsum)
{
    __shared__ int s[256];
    const int tid = threadIdx.x;
    const int gid = blockIdx.x * 256 + tid;
    int v = (gid < N_NODES) ? deg[gid] : 0;
    s[tid] = v;
    __syncthreads();
    for (int off = 1; off < 256; off <<= 1) {
        int t = (tid >= off) ? s[tid - off] : 0;
        __syncthreads();
        if (tid >= off) s[tid] += t;
        __syncthreads();
    }
    if (gid < N_NODES) row_start[gid] = s[tid] - v;    // chunk-exclusive
    if (tid == 255) bsum[blockIdx.x] = s[255];         // chunk total
}

// stage 2: one block scans the 196 chunk totals (exclusive, in place)
__global__ __launch_bounds__(256) void scan2_kernel(int* __restrict__ bsum,
                                                    int* __restrict__ row_start)
{
    __shared__ int s[256];
    const int tid = threadIdx.x;
    int v = (tid < SCAN_BLK) ? bsum[tid] : 0;
    s[tid] = v;
    __syncthreads();
    for (int off = 1; off < 256; off <<= 1) {
        int t = (tid >= off) ? s[tid - off] : 0;
        __syncthreads();
        if (tid >= off) s[tid] += t;
        __syncthreads();
    }
    if (tid < SCAN_BLK) bsum[tid] = s[tid] - v;        // exclusive
    if (tid == 255) row_start[N_NODES] = s[255];       // grand total = N_EDGES
}

// stage 3: add chunk offsets, init cursor
__global__ __launch_bounds__(256) void scan3_kernel(int* __restrict__ row_start,
                                                    const int* __restrict__ bsum,
                                                    int* __restrict__ cursor)
{
    int gid = blockIdx.x * 256 + threadIdx.x;
    if (gid < N_NODES) {
        int v = row_start[gid] + bsum[blockIdx.x];
        row_start[gid] = v;
        cursor[gid] = v;
    }
}

__global__ __launch_bounds__(256) void fill_kernel(const int* __restrict__ ei,
                                                   int* __restrict__ cursor,
                                                   int* __restrict__ csr_src)
{
    int e = blockIdx.x * 256 + threadIdx.x;
    if (e >= N_EDGES) return;
    int d = ei[N_EDGES + e];
    int pos = atomicAdd(&cursor[d], 1);
    csr_src[pos] = ei[e];
}

// ---------------- fused: [BN+ReLU on reads] + gather + mlp1 + ReLU ---------
// one wave per node for the gather; z row goes to LDS, then 64x64 GEMV.
template<bool HASBN>
__global__ __launch_bounds__(256) void layerA_kernel(
    const float* __restrict__ hin, const int* __restrict__ csr_src,
    const int* __restrict__ row_start,
    const float* __restrict__ stats, const float* __restrict__ gamma,
    const float* __restrict__ beta,
    const float* __restrict__ eps, int layer,
    const float* __restrict__ w1, const float* __restrict__ b1,
    float* __restrict__ y1)
{
    __shared__ float wl[HIDDEN * HIDDEN];   // 16 KB
    __shared__ float xs[4 * HIDDEN];
    for (int i = threadIdx.x; i < HIDDEN * HIDDEN; i += 256)
        wl[i] = w1[i];
    const int col = threadIdx.x & 63;
    const int wv  = threadIdx.x >> 6;
    const float bias = b1[col];
    float A = 1.0f, B = 0.0f;
    if (HASBN) {
        const float invN = 1.0f / (float)N_NODES;
        float mean = stats[col] * invN;
        float var  = stats[HIDDEN + col] * invN - mean * mean;
        float inv  = rsqrtf(fmaxf(var, 0.f) + BN_EPS);
        A = inv * gamma[col];
        B = beta[col] - mean * A;
    }
    const float sf = 1.0f + eps[layer];
    for (int base = blockIdx.x * 4; base < N_NODES; base += gridDim.x * 4) {
        __syncthreads();                        // xs reuse from prev iter
        const int node = base + wv;             // N_NODES % 4 == 0 -> valid
        const int s0 = row_start[node];
        const int s1 = row_start[node + 1];
        float v = hin[(size_t)node * HIDDEN + col];
        if (HASBN) v = fmaxf(fmaf(v, A, B), 0.f);
        float acc = sf * v;
        for (int j = s0; j < s1; ++j) {
            int s = csr_src[j];
            float u = hin[(size_t)s * HIDDEN + col];
            if (HASBN) u = fmaxf(fmaf(u, A, B), 0.f);
            acc += u;
        }
        xs[wv * HIDDEN + col] = acc;
        __syncthreads();
        float o = bias;
        for (int k = 0; k < HIDDEN; ++k)
            o = fmaf(xs[wv * HIDDEN + k], wl[k * HIDDEN + col], o);
        y1[(size_t)node * HIDDEN + col] = fmaxf(o, 0.f);
    }
}

// ---------------- mlp2 + BN-stats accumulation -----------------------------
__global__ __launch_bounds__(256) void layerB_kernel(
    const float* __restrict__ y1, const float* __restrict__ w2,
    const float* __restrict__ b2, float* __restrict__ hout,
    float* __restrict__ stats)
{
    __shared__ float wl[HIDDEN * HIDDEN];
    __shared__ float xs[4 * HIDDEN];
    __shared__ float red[512];
    for (int i = threadIdx.x; i < HIDDEN * HIDDEN; i += 256)
        wl[i] = w2[i];
    const int col = threadIdx.x & 63;
    const int row = threadIdx.x >> 6;
    const float bias = b2[col];
    float s = 0.f, s2 = 0.f;
    for (int base = blockIdx.x * 4; base < N_NODES; base += gridDim.x * 4) {
        __syncthreads();
        const int node = base + row;
        xs[threadIdx.x] = y1[(size_t)node * HIDDEN + col];
        __syncthreads();
        float acc = bias;
        for (int k = 0; k < HIDDEN; ++k)
            acc = fmaf(xs[row * HIDDEN + k], wl[k * HIDDEN + col], acc);
        hout[(size_t)node * HIDDEN + col] = acc;
        s += acc; s2 += acc * acc;
    }
    __syncthreads();
    red[threadIdx.x] = s;
    red[256 + threadIdx.x] = s2;
    __syncthreads();
    if (row == 0) {
        float ts  = red[col] + red[64 + col] + red[128 + col] + red[192 + col];
        float ts2 = red[256 + col] + red[320 + col] + red[384 + col] + red[448 + col];
        atomicAdd(&stats[col], ts);
        atomicAdd(&stats[HIDDEN + col], ts2);
    }
}

__device__ __forceinline__ int lbound(const int* __restrict__ a, int n, int v)
{
    int lo = 0, hi = n;
    while (lo < hi) { int m = (lo + hi) >> 1; if (a[m] < v) lo = m + 1; else hi = m; }
    return lo;
}

// ---------------- mean pool per graph, BN+ReLU of last layer folded in ----
__global__ __launch_bounds__(256) void pool_kernel(
    const float* __restrict__ hpre, const int* __restrict__ batch,
    const float* __restrict__ stats, const float* __restrict__ gamma,
    const float* __restrict__ beta, float* __restrict__ pooled)
{
    __shared__ int bounds[2];
    __shared__ float red[256];
    const int g = blockIdx.x;
    if (threadIdx.x < 2)
        bounds[threadIdx.x] = lbound(batch, N_NODES, g + threadIdx.x);
    __syncthreads();
    const int start = bounds[0], end = bounds[1];
    const int col = threadIdx.x & 63;
    const int row = threadIdx.x >> 6;
    const float invN = 1.0f / (float)N_NODES;
    float mean = stats[col] * invN;
    float var  = stats[HIDDEN + col] * invN - mean * mean;
    float inv  = rsqrtf(fmaxf(var, 0.f) + BN_EPS);
    float A = inv * gamma[col];
    float B = beta[col] - mean * A;
    float s = 0.f;
    for (int r = start + row; r < end; r += 4)
        s += fmaxf(fmaf(hpre[(size_t)r * HIDDEN + col], A, B), 0.f);
    red[threadIdx.x] = s;
    __syncthreads();
    if (row == 0) {
        float t = red[col] + red[64 + col] + red[128 + col] + red[192 + col];
        pooled[(size_t)g * HIDDEN + col] = t / fmaxf((float)(end - start), 1.0f);
    }
}

// ---------------- out = pooled @ lin_w + lin_b ------------------------------
__global__ void out_kernel(const float* __restrict__ pooled,
                           const float* __restrict__ w, const float* __restrict__ b,
                           float* __restrict__ out)
{
    int gid = blockIdx.x * blockDim.x + threadIdx.x;
    if (gid >= N_GRAPHS * N_CLASSES) return;
    int g = gid / N_CLASSES;
    int c = gid - g * N_CLASSES;
    float acc = b[c];
    for (int j = 0; j < HIDDEN; ++j)
        acc = fmaf(pooled[(size_t)g * HIDDEN + j], w[j * N_CLASSES + c], acc);
    out[gid] = acc;
}

extern "C" void kernel_launch(void* const* d_in, const int* in_sizes, int n_in,
                              void* d_out, int out_size, void* d_ws, size_t ws_size,
                              hipStream_t stream)
{
    const float* x       = (const float*)d_in[0];
    const int*   ei      = (const int*)d_in[1];   // [2, N_EDGES]: src then dst
    const int*   batch   = (const int*)d_in[2];
    const float* enc_w   = (const float*)d_in[3];
    const float* enc_b   = (const float*)d_in[4];
    const float* eps     = (const float*)d_in[5];
    const float* conv_w1 = (const float*)d_in[6];
    const float* conv_b1 = (const float*)d_in[7];
    const float* conv_w2 = (const float*)d_in[8];
    const float* conv_b2 = (const float*)d_in[9];
    const float* bn_g    = (const float*)d_in[10];
    const float* bn_b    = (const float*)d_in[11];
    const float* lin_w   = (const float*)d_in[12];
    const float* lin_b   = (const float*)d_in[13];
    float* out = (float*)d_out;

    char* ws = (char*)d_ws;
    const size_t HB = (size_t)N_NODES * HIDDEN * sizeof(float);  // 12.8 MB
    size_t off = 0;
    float* P      = (float*)(ws + off); off += HB;          // ping
    float* Q      = (float*)(ws + off); off += HB;          // pong
    float* stats  = (float*)(ws + off); off += N_LAYERS * 2 * HIDDEN * sizeof(float);
    float* pooled = (float*)(ws + off); off += (size_t)N_GRAPHS * HIDDEN * sizeof(float);
    int* deg       = (int*)(ws + off); off += 50176 * sizeof(int);
    int* row_start = (int*)(ws + off); off += 50176 * sizeof(int);   // N_NODES+1 used
    int* cursor    = (int*)(ws + off); off += 50176 * sizeof(int);
    int* bsum      = (int*)(ws + off); off += 256 * sizeof(int);
    int* csr_src   = (int*)(ws + off); off += (size_t)N_EDGES * sizeof(int);

    hipMemsetAsync(deg, 0, N_NODES * sizeof(int), stream);
    hipMemsetAsync(stats, 0, N_LAYERS * 2 * HIDDEN * sizeof(float), stream);

    enc_kernel<<<1024, 256, 0, stream>>>(x, enc_w, enc_b, P);

    hist_kernel<<<(N_EDGES + 255) / 256, 256, 0, stream>>>(ei, deg);
    scan1_kernel<<<SCAN_BLK, 256, 0, stream>>>(deg, row_start, bsum);
    scan2_kernel<<<1, 256, 0, stream>>>(bsum, row_start);
    scan3_kernel<<<SCAN_BLK, 256, 0, stream>>>(row_start, bsum, cursor);
    fill_kernel<<<(N_EDGES + 255) / 256, 256, 0, stream>>>(ei, cursor, csr_src);

    for (int l = 0; l < N_LAYERS; ++l) {
        const float* w1 = conv_w1 + (size_t)l * HIDDEN * HIDDEN;
        const float* b1 = conv_b1 + (size_t)l * HIDDEN;
        const float* w2 = conv_w2 + (size_t)l * HIDDEN * HIDDEN;
        const float* b2 = conv_b2 + (size_t)l * HIDDEN;
        if (l == 0)
            layerA_kernel<false><<<2048, 256, 0, stream>>>(
                P, csr_src, row_start, nullptr, nullptr, nullptr, eps, l, w1, b1, Q);
        else
            layerA_kernel<true><<<2048, 256, 0, stream>>>(
                P, csr_src, row_start,
                stats + (size_t)(l - 1) * 2 * HIDDEN,
                bn_g + (size_t)(l - 1) * HIDDEN, bn_b + (size_t)(l - 1) * HIDDEN,
                eps, l, w1, b1, Q);
        layerB_kernel<<<2048, 256, 0, stream>>>(
            Q, w2, b2, P, stats + (size_t)l * 2 * HIDDEN);
    }

    pool_kernel<<<N_GRAPHS, 256, 0, stream>>>(
        P, batch, stats + (size_t)(N_LAYERS - 1) * 2 * HIDDEN,
        bn_g + (size_t)(N_LAYERS - 1) * HIDDEN, bn_b + (size_t)(N_LAYERS - 1) * HIDDEN,
        pooled);
    out_kernel<<<(N_GRAPHS * N_CLASSES + 255) / 256, 256, 0, stream>>>(pooled, lin_w, lin_b, out);
}

// Round 4
// 379.930 us; speedup vs baseline: 2.3565x; 1.5944x over previous
//
#include <hip/hip_runtime.h>

#define N_NODES   50000
#define N_EDGES   800000
#define N_FEAT    128
#define HIDDEN    64
#define N_LAYERS  3
#define N_GRAPHS  512
#define N_CLASSES 10
#define BN_EPS    1e-5f
#define SCAN_BLK  196   // ceil(N_NODES/256)
#define PITCH     68    // 64 + 4: 16B-aligned rows, balanced LDS banks
#define EPITCH    132   // 128 + 4

// ---------------- encoder: h = x @ enc_w + enc_b  ([50000,128]@[128,64]) ---
// wave-autonomous, 4 nodes/wave, transposed weights in LDS, b128 reads
__global__ __launch_bounds__(256) void enc_kernel(
    const float* __restrict__ x, const float* __restrict__ w,
    const float* __restrict__ b, float* __restrict__ h)
{
    __shared__ __align__(16) float wT[HIDDEN * EPITCH];   // 33.8 KB
    __shared__ __align__(16) float xb[4][4][N_FEAT];      // 8 KB
    for (int i = threadIdx.x; i < N_FEAT * HIDDEN; i += 256) {
        int k = i >> 6, c = i & 63;
        wT[c * EPITCH + k] = w[i];
    }
    const int col = threadIdx.x & 63;
    const int wv  = threadIdx.x >> 6;
    const float bias = b[col];
    __syncthreads();
    const int nwaves = gridDim.x * 4;
    for (int grp = blockIdx.x * 4 + wv; grp < N_NODES / 4; grp += nwaves) {
        const int nbase = grp * 4;
        #pragma unroll
        for (int n = 0; n < 4; ++n) {
            xb[wv][n][col]      = x[(size_t)(nbase + n) * N_FEAT + col];
            xb[wv][n][64 + col] = x[(size_t)(nbase + n) * N_FEAT + 64 + col];
        }
        float o0 = bias, o1 = bias, o2 = bias, o3 = bias;
        #pragma unroll 4
        for (int kc = 0; kc < N_FEAT / 4; ++kc) {
            float4 w4 = *(const float4*)&wT[col * EPITCH + 4 * kc];
            float4 z0 = *(const float4*)&xb[wv][0][4 * kc];
            float4 z1 = *(const float4*)&xb[wv][1][4 * kc];
            float4 z2 = *(const float4*)&xb[wv][2][4 * kc];
            float4 z3 = *(const float4*)&xb[wv][3][4 * kc];
            o0 = fmaf(w4.x, z0.x, fmaf(w4.y, z0.y, fmaf(w4.z, z0.z, fmaf(w4.w, z0.w, o0))));
            o1 = fmaf(w4.x, z1.x, fmaf(w4.y, z1.y, fmaf(w4.z, z1.z, fmaf(w4.w, z1.w, o1))));
            o2 = fmaf(w4.x, z2.x, fmaf(w4.y, z2.y, fmaf(w4.z, z2.z, fmaf(w4.w, z2.w, o2))));
            o3 = fmaf(w4.x, z3.x, fmaf(w4.y, z3.y, fmaf(w4.z, z3.z, fmaf(w4.w, z3.w, o3))));
        }
        h[(size_t)(nbase + 0) * HIDDEN + col] = o0;
        h[(size_t)(nbase + 1) * HIDDEN + col] = o1;
        h[(size_t)(nbase + 2) * HIDDEN + col] = o2;
        h[(size_t)(nbase + 3) * HIDDEN + col] = o3;
    }
}

// ---------------- CSR build ------------------------------------------------
__global__ __launch_bounds__(256) void hist_kernel(const int* __restrict__ ei,
                                                   int* __restrict__ deg)
{
    int e = blockIdx.x * 256 + threadIdx.x;
    if (e < N_EDGES) atomicAdd(&deg[ei[N_EDGES + e]], 1);
}

__global__ __launch_bounds__(256) void scan1_kernel(const int* __restrict__ deg,
                                                    int* __restrict__ row_start,
                                                    int* __restrict__ bsum)
{
    __shared__ int s[256];
    const int tid = threadIdx.x;
    const int gid = blockIdx.x * 256 + tid;
    int v = (gid < N_NODES) ? deg[gid] : 0;
    s[tid] = v;
    __syncthreads();
    for (int off = 1; off < 256; off <<= 1) {
        int t = (tid >= off) ? s[tid - off] : 0;
        __syncthreads();
        if (tid >= off) s[tid] += t;
        __syncthreads();
    }
    if (gid < N_NODES) row_start[gid] = s[tid] - v;
    if (tid == 255) bsum[blockIdx.x] = s[255];
}

__global__ __launch_bounds__(256) void scan2_kernel(int* __restrict__ bsum,
                                                    int* __restrict__ row_start)
{
    __shared__ int s[256];
    const int tid = threadIdx.x;
    int v = (tid < SCAN_BLK) ? bsum[tid] : 0;
    s[tid] = v;
    __syncthreads();
    for (int off = 1; off < 256; off <<= 1) {
        int t = (tid >= off) ? s[tid - off] : 0;
        __syncthreads();
        if (tid >= off) s[tid] += t;
        __syncthreads();
    }
    if (tid < SCAN_BLK) bsum[tid] = s[tid] - v;
    if (tid == 255) row_start[N_NODES] = s[255];
}

__global__ __launch_bounds__(256) void scan3_kernel(int* __restrict__ row_start,
                                                    const int* __restrict__ bsum,
                                                    int* __restrict__ cursor)
{
    int gid = blockIdx.x * 256 + threadIdx.x;
    if (gid < N_NODES) {
        int v = row_start[gid] + bsum[blockIdx.x];
        row_start[gid] = v;
        cursor[gid] = v;
    }
}

__global__ __launch_bounds__(256) void fill_kernel(const int* __restrict__ ei,
                                                   int* __restrict__ cursor,
                                                   int* __restrict__ csr_src)
{
    int e = blockIdx.x * 256 + threadIdx.x;
    if (e >= N_EDGES) return;
    int d = ei[N_EDGES + e];
    int pos = atomicAdd(&cursor[d], 1);
    csr_src[pos] = ei[e];
}

// ---------------- fused GIN layer -------------------------------------------
// per wave: [BN+ReLU folded reads] gather -> MLP1+ReLU -> MLP2 -> store+stats
// wave-autonomous: no __syncthreads in the main loop.
template<bool HASBN>
__global__ __launch_bounds__(256) void layer_kernel(
    const float* __restrict__ hin, const int* __restrict__ csr_src,
    const int* __restrict__ row_start,
    const float* __restrict__ stats_prev, const float* __restrict__ gamma,
    const float* __restrict__ beta,
    const float* __restrict__ eps, int layer,
    const float* __restrict__ w1, const float* __restrict__ b1,
    const float* __restrict__ w2, const float* __restrict__ b2,
    float* __restrict__ hout, float* __restrict__ stats_cur)
{
    __shared__ __align__(16) float wT1[HIDDEN * PITCH];   // 17.4 KB
    __shared__ __align__(16) float wT2[HIDDEN * PITCH];   // 17.4 KB
    __shared__ __align__(16) float zb[4][4][HIDDEN];      // 4 KB, wave-private slots
    for (int i = threadIdx.x; i < HIDDEN * HIDDEN; i += 256) {
        int k = i >> 6, c = i & 63;
        wT1[c * PITCH + k] = w1[i];
        wT2[c * PITCH + k] = w2[i];
    }
    const int col = threadIdx.x & 63;
    const int wv  = threadIdx.x >> 6;
    float A = 1.0f, Bc = 0.0f;
    if (HASBN) {
        const float invN = 1.0f / (float)N_NODES;
        float mean = stats_prev[col] * invN;
        float var  = stats_prev[HIDDEN + col] * invN - mean * mean;
        float inv  = rsqrtf(fmaxf(var, 0.f) + BN_EPS);
        A = inv * gamma[col];
        Bc = beta[col] - mean * A;
    }
    const float sf  = 1.0f + eps[layer];
    const float b1c = b1[col], b2c = b2[col];
    __syncthreads();

    float s = 0.f, s2 = 0.f;
    const int nwaves = gridDim.x * 4;
    for (int grp = blockIdx.x * 4 + wv; grp < N_NODES / 4; grp += nwaves) {
        const int nbase = grp * 4;
        // ---- gather 4 nodes into wave-private LDS slot ----
        for (int n = 0; n < 4; ++n) {
            const int node = nbase + n;
            const int s0 = row_start[node];
            const int s1 = row_start[node + 1];
            float v = hin[(size_t)node * HIDDEN + col];
            if (HASBN) v = fmaxf(fmaf(v, A, Bc), 0.f);
            float a0 = sf * v, a1 = 0.f, a2 = 0.f, a3 = 0.f;
            for (int jb = s0; jb < s1; jb += 64) {
                int m = s1 - jb; if (m > 64) m = 64;
                int idx = csr_src[jb + (col < m ? col : m - 1)];  // 1 coalesced load
                int j = 0;
                for (; j + 4 <= m; j += 4) {
                    int i0 = __shfl(idx, j + 0), i1 = __shfl(idx, j + 1);
                    int i2 = __shfl(idx, j + 2), i3 = __shfl(idx, j + 3);
                    float u0 = hin[(size_t)i0 * HIDDEN + col];
                    float u1 = hin[(size_t)i1 * HIDDEN + col];
                    float u2 = hin[(size_t)i2 * HIDDEN + col];
                    float u3 = hin[(size_t)i3 * HIDDEN + col];
                    if (HASBN) {
                        u0 = fmaxf(fmaf(u0, A, Bc), 0.f);
                        u1 = fmaxf(fmaf(u1, A, Bc), 0.f);
                        u2 = fmaxf(fmaf(u2, A, Bc), 0.f);
                        u3 = fmaxf(fmaf(u3, A, Bc), 0.f);
                    }
                    a0 += u0; a1 += u1; a2 += u2; a3 += u3;
                }
                for (; j < m; ++j) {
                    int i0 = __shfl(idx, j);
                    float u = hin[(size_t)i0 * HIDDEN + col];
                    if (HASBN) u = fmaxf(fmaf(u, A, Bc), 0.f);
                    a0 += u;
                }
            }
            zb[wv][n][col] = (a0 + a1) + (a2 + a3);
        }
        // ---- MLP1: o = relu(z @ w1 + b1) (wave-private LDS, no barrier) ----
        float o0 = b1c, o1 = b1c, o2 = b1c, o3 = b1c;
        #pragma unroll 4
        for (int kc = 0; kc < HIDDEN / 4; ++kc) {
            float4 w4 = *(const float4*)&wT1[col * PITCH + 4 * kc];
            float4 z0 = *(const float4*)&zb[wv][0][4 * kc];
            float4 z1 = *(const float4*)&zb[wv][1][4 * kc];
            float4 z2 = *(const float4*)&zb[wv][2][4 * kc];
            float4 z3 = *(const float4*)&zb[wv][3][4 * kc];
            o0 = fmaf(w4.x, z0.x, fmaf(w4.y, z0.y, fmaf(w4.z, z0.z, fmaf(w4.w, z0.w, o0))));
            o1 = fmaf(w4.x, z1.x, fmaf(w4.y, z1.y, fmaf(w4.z, z1.z, fmaf(w4.w, z1.w, o1))));
            o2 = fmaf(w4.x, z2.x, fmaf(w4.y, z2.y, fmaf(w4.z, z2.z, fmaf(w4.w, z2.w, o2))));
            o3 = fmaf(w4.x, z3.x, fmaf(w4.y, z3.y, fmaf(w4.z, z3.z, fmaf(w4.w, z3.w, o3))));
        }
        zb[wv][0][col] = fmaxf(o0, 0.f);
        zb[wv][1][col] = fmaxf(o1, 0.f);
        zb[wv][2][col] = fmaxf(o2, 0.f);
        zb[wv][3][col] = fmaxf(o3, 0.f);
        // ---- MLP2: p = y @ w2 + b2 ----
        float p0 = b2c, p1 = b2c, p2 = b2c, p3 = b2c;
        #pragma unroll 4
        for (int kc = 0; kc < HIDDEN / 4; ++kc) {
            float4 w4 = *(const float4*)&wT2[col * PITCH + 4 * kc];
            float4 z0 = *(const float4*)&zb[wv][0][4 * kc];
            float4 z1 = *(const float4*)&zb[wv][1][4 * kc];
            float4 z2 = *(const float4*)&zb[wv][2][4 * kc];
            float4 z3 = *(const float4*)&zb[wv][3][4 * kc];
            p0 = fmaf(w4.x, z0.x, fmaf(w4.y, z0.y, fmaf(w4.z, z0.z, fmaf(w4.w, z0.w, p0))));
            p1 = fmaf(w4.x, z1.x, fmaf(w4.y, z1.y, fmaf(w4.z, z1.z, fmaf(w4.w, z1.w, p1))));
            p2 = fmaf(w4.x, z2.x, fmaf(w4.y, z2.y, fmaf(w4.z, z2.z, fmaf(w4.w, z2.w, p2))));
            p3 = fmaf(w4.x, z3.x, fmaf(w4.y, z3.y, fmaf(w4.z, z3.z, fmaf(w4.w, z3.w, p3))));
        }
        hout[(size_t)(nbase + 0) * HIDDEN + col] = p0;
        hout[(size_t)(nbase + 1) * HIDDEN + col] = p1;
        hout[(size_t)(nbase + 2) * HIDDEN + col] = p2;
        hout[(size_t)(nbase + 3) * HIDDEN + col] = p3;
        s  += ((p0 + p1) + (p2 + p3));
        s2 += ((p0 * p0 + p1 * p1) + (p2 * p2 + p3 * p3));
    }
    // ---- block-level BN-stats reduction (reuse wT1 as scratch) ----
    __syncthreads();
    float* red = wT1;
    red[threadIdx.x] = s;
    red[256 + threadIdx.x] = s2;
    __syncthreads();
    if (wv == 0) {
        float ts  = red[col] + red[64 + col] + red[128 + col] + red[192 + col];
        float ts2 = red[256 + col] + red[320 + col] + red[384 + col] + red[448 + col];
        atomicAdd(&stats_cur[col], ts);
        atomicAdd(&stats_cur[HIDDEN + col], ts2);
    }
}

__device__ __forceinline__ int lbound(const int* __restrict__ a, int n, int v)
{
    int lo = 0, hi = n;
    while (lo < hi) { int m = (lo + hi) >> 1; if (a[m] < v) lo = m + 1; else hi = m; }
    return lo;
}

// ---------------- mean pool per graph, BN+ReLU of last layer folded in ----
__global__ __launch_bounds__(256) void pool_kernel(
    const float* __restrict__ hpre, const int* __restrict__ batch,
    const float* __restrict__ stats, const float* __restrict__ gamma,
    const float* __restrict__ beta, float* __restrict__ pooled)
{
    __shared__ int bounds[2];
    __shared__ float red[256];
    const int g = blockIdx.x;
    if (threadIdx.x < 2)
        bounds[threadIdx.x] = lbound(batch, N_NODES, g + threadIdx.x);
    __syncthreads();
    const int start = bounds[0], end = bounds[1];
    const int col = threadIdx.x & 63;
    const int row = threadIdx.x >> 6;
    const float invN = 1.0f / (float)N_NODES;
    float mean = stats[col] * invN;
    float var  = stats[HIDDEN + col] * invN - mean * mean;
    float inv  = rsqrtf(fmaxf(var, 0.f) + BN_EPS);
    float A = inv * gamma[col];
    float B = beta[col] - mean * A;
    float s = 0.f;
    for (int r = start + row; r < end; r += 4)
        s += fmaxf(fmaf(hpre[(size_t)r * HIDDEN + col], A, B), 0.f);
    red[threadIdx.x] = s;
    __syncthreads();
    if (row == 0) {
        float t = red[col] + red[64 + col] + red[128 + col] + red[192 + col];
        pooled[(size_t)g * HIDDEN + col] = t / fmaxf((float)(end - start), 1.0f);
    }
}

// ---------------- out = pooled @ lin_w + lin_b ------------------------------
__global__ void out_kernel(const float* __restrict__ pooled,
                           const float* __restrict__ w, const float* __restrict__ b,
                           float* __restrict__ out)
{
    int gid = blockIdx.x * blockDim.x + threadIdx.x;
    if (gid >= N_GRAPHS * N_CLASSES) return;
    int g = gid / N_CLASSES;
    int c = gid - g * N_CLASSES;
    float acc = b[c];
    for (int j = 0; j < HIDDEN; ++j)
        acc = fmaf(pooled[(size_t)g * HIDDEN + j], w[j * N_CLASSES + c], acc);
    out[gid] = acc;
}

extern "C" void kernel_launch(void* const* d_in, const int* in_sizes, int n_in,
                              void* d_out, int out_size, void* d_ws, size_t ws_size,
                              hipStream_t stream)
{
    const float* x       = (const float*)d_in[0];
    const int*   ei      = (const int*)d_in[1];   // [2, N_EDGES]: src then dst
    const int*   batch   = (const int*)d_in[2];
    const float* enc_w   = (const float*)d_in[3];
    const float* enc_b   = (const float*)d_in[4];
    const float* eps     = (const float*)d_in[5];
    const float* conv_w1 = (const float*)d_in[6];
    const float* conv_b1 = (const float*)d_in[7];
    const float* conv_w2 = (const float*)d_in[8];
    const float* conv_b2 = (const float*)d_in[9];
    const float* bn_g    = (const float*)d_in[10];
    const float* bn_b    = (const float*)d_in[11];
    const float* lin_w   = (const float*)d_in[12];
    const float* lin_b   = (const float*)d_in[13];
    float* out = (float*)d_out;

    char* ws = (char*)d_ws;
    const size_t HB = (size_t)N_NODES * HIDDEN * sizeof(float);  // 12.8 MB
    size_t off = 0;
    float* P      = (float*)(ws + off); off += HB;          // ping
    float* Q      = (float*)(ws + off); off += HB;          // pong
    float* stats  = (float*)(ws + off); off += N_LAYERS * 2 * HIDDEN * sizeof(float);
    float* pooled = (float*)(ws + off); off += (size_t)N_GRAPHS * HIDDEN * sizeof(float);
    int* deg       = (int*)(ws + off); off += 50176 * sizeof(int);
    int* row_start = (int*)(ws + off); off += 50176 * sizeof(int);   // N_NODES+1 used
    int* cursor    = (int*)(ws + off); off += 50176 * sizeof(int);
    int* bsum      = (int*)(ws + off); off += 256 * sizeof(int);
    int* csr_src   = (int*)(ws + off); off += (size_t)N_EDGES * sizeof(int);

    hipMemsetAsync(deg, 0, N_NODES * sizeof(int), stream);
    hipMemsetAsync(stats, 0, N_LAYERS * 2 * HIDDEN * sizeof(float), stream);

    enc_kernel<<<768, 256, 0, stream>>>(x, enc_w, enc_b, P);

    hist_kernel<<<(N_EDGES + 255) / 256, 256, 0, stream>>>(ei, deg);
    scan1_kernel<<<SCAN_BLK, 256, 0, stream>>>(deg, row_start, bsum);
    scan2_kernel<<<1, 256, 0, stream>>>(bsum, row_start);
    scan3_kernel<<<SCAN_BLK, 256, 0, stream>>>(row_start, bsum, cursor);
    fill_kernel<<<(N_EDGES + 255) / 256, 256, 0, stream>>>(ei, cursor, csr_src);

    const float* curin = P;
    float* curout = Q;
    for (int l = 0; l < N_LAYERS; ++l) {
        const float* w1 = conv_w1 + (size_t)l * HIDDEN * HIDDEN;
        const float* b1 = conv_b1 + (size_t)l * HIDDEN;
        const float* w2 = conv_w2 + (size_t)l * HIDDEN * HIDDEN;
        const float* b2 = conv_b2 + (size_t)l * HIDDEN;
        if (l == 0)
            layer_kernel<false><<<1024, 256, 0, stream>>>(
                curin, csr_src, row_start, nullptr, nullptr, nullptr,
                eps, l, w1, b1, w2, b2, curout, stats);
        else
            layer_kernel<true><<<1024, 256, 0, stream>>>(
                curin, csr_src, row_start,
                stats + (size_t)(l - 1) * 2 * HIDDEN,
                bn_g + (size_t)(l - 1) * HIDDEN, bn_b + (size_t)(l - 1) * HIDDEN,
                eps, l, w1, b1, w2, b2, curout, stats + (size_t)l * 2 * HIDDEN);
        const float* t = curout; curout = (float*)curin; curin = t;
    }
    // after 3 layers: final pre-BN activations are in Q (P->Q->P->Q)

    pool_kernel<<<N_GRAPHS, 256, 0, stream>>>(
        Q, batch, stats + (size_t)(N_LAYERS - 1) * 2 * HIDDEN,
        bn_g + (size_t)(N_LAYERS - 1) * HIDDEN, bn_b + (size_t)(N_LAYERS - 1) * HIDDEN,
        pooled);
    out_kernel<<<(N_GRAPHS * N_CLASSES + 255) / 256, 256, 0, stream>>>(pooled, lin_w, lin_b, out);
}

// Round 5
// 337.996 us; speedup vs baseline: 2.6488x; 1.1241x over previous
//
#include <hip/hip_runtime.h>

#define N_NODES   50000
#define N_EDGES   800000
#define N_FEAT    128
#define HIDDEN    64
#define N_LAYERS  3
#define N_GRAPHS  512
#define N_CLASSES 10
#define BN_EPS    1e-5f
#define SCAN_BLK  196   // ceil(N_NODES/256)
#define PITCH     68    // 64 + 4: 16B-aligned rows, balanced LDS banks
#define EPITCH    132   // 128 + 4
#define LWAVES    8     // waves per block in enc/layer kernels (512 threads)

// ---------------- encoder: h = x @ enc_w + enc_b  ([50000,128]@[128,64]) ---
// wave-autonomous, 4 nodes/wave, transposed weights in LDS, b128 reads
__global__ __launch_bounds__(512, 6) void enc_kernel(
    const float* __restrict__ x, const float* __restrict__ w,
    const float* __restrict__ b, float* __restrict__ h)
{
    __shared__ __align__(16) float wT[HIDDEN * EPITCH];        // 33.8 KB
    __shared__ __align__(16) float xb[LWAVES][4][N_FEAT];      // 16 KB
    for (int i = threadIdx.x; i < N_FEAT * HIDDEN; i += 512) {
        int k = i >> 6, c = i & 63;
        wT[c * EPITCH + k] = w[i];
    }
    const int col = threadIdx.x & 63;
    const int wv  = threadIdx.x >> 6;
    const float bias = b[col];
    __syncthreads();
    const int nwaves = gridDim.x * LWAVES;
    for (int grp = blockIdx.x * LWAVES + wv; grp < N_NODES / 4; grp += nwaves) {
        const int nbase = grp * 4;
        #pragma unroll
        for (int n = 0; n < 4; ++n) {
            xb[wv][n][col]      = x[(size_t)(nbase + n) * N_FEAT + col];
            xb[wv][n][64 + col] = x[(size_t)(nbase + n) * N_FEAT + 64 + col];
        }
        float o0 = bias, o1 = bias, o2 = bias, o3 = bias;
        #pragma unroll 4
        for (int kc = 0; kc < N_FEAT / 4; ++kc) {
            float4 w4 = *(const float4*)&wT[col * EPITCH + 4 * kc];
            float4 z0 = *(const float4*)&xb[wv][0][4 * kc];
            float4 z1 = *(const float4*)&xb[wv][1][4 * kc];
            float4 z2 = *(const float4*)&xb[wv][2][4 * kc];
            float4 z3 = *(const float4*)&xb[wv][3][4 * kc];
            o0 = fmaf(w4.x, z0.x, fmaf(w4.y, z0.y, fmaf(w4.z, z0.z, fmaf(w4.w, z0.w, o0))));
            o1 = fmaf(w4.x, z1.x, fmaf(w4.y, z1.y, fmaf(w4.z, z1.z, fmaf(w4.w, z1.w, o1))));
            o2 = fmaf(w4.x, z2.x, fmaf(w4.y, z2.y, fmaf(w4.z, z2.z, fmaf(w4.w, z2.w, o2))));
            o3 = fmaf(w4.x, z3.x, fmaf(w4.y, z3.y, fmaf(w4.z, z3.z, fmaf(w4.w, z3.w, o3))));
        }
        h[(size_t)(nbase + 0) * HIDDEN + col] = o0;
        h[(size_t)(nbase + 1) * HIDDEN + col] = o1;
        h[(size_t)(nbase + 2) * HIDDEN + col] = o2;
        h[(size_t)(nbase + 3) * HIDDEN + col] = o3;
    }
}

// ---------------- CSR build ------------------------------------------------
__global__ __launch_bounds__(256) void hist_kernel(const int* __restrict__ ei,
                                                   int* __restrict__ deg)
{
    int e = blockIdx.x * 256 + threadIdx.x;
    if (e < N_EDGES) atomicAdd(&deg[ei[N_EDGES + e]], 1);
}

__global__ __launch_bounds__(256) void scan1_kernel(const int* __restrict__ deg,
                                                    int* __restrict__ row_start,
                                                    int* __restrict__ bsum)
{
    __shared__ int s[256];
    const int tid = threadIdx.x;
    const int gid = blockIdx.x * 256 + tid;
    int v = (gid < N_NODES) ? deg[gid] : 0;
    s[tid] = v;
    __syncthreads();
    for (int off = 1; off < 256; off <<= 1) {
        int t = (tid >= off) ? s[tid - off] : 0;
        __syncthreads();
        if (tid >= off) s[tid] += t;
        __syncthreads();
    }
    if (gid < N_NODES) row_start[gid] = s[tid] - v;
    if (tid == 255) bsum[blockIdx.x] = s[255];
}

__global__ __launch_bounds__(256) void scan2_kernel(int* __restrict__ bsum,
                                                    int* __restrict__ row_start)
{
    __shared__ int s[256];
    const int tid = threadIdx.x;
    int v = (tid < SCAN_BLK) ? bsum[tid] : 0;
    s[tid] = v;
    __syncthreads();
    for (int off = 1; off < 256; off <<= 1) {
        int t = (tid >= off) ? s[tid - off] : 0;
        __syncthreads();
        if (tid >= off) s[tid] += t;
        __syncthreads();
    }
    if (tid < SCAN_BLK) bsum[tid] = s[tid] - v;
    if (tid == 255) row_start[N_NODES] = s[255];
}

__global__ __launch_bounds__(256) void scan3_kernel(int* __restrict__ row_start,
                                                    const int* __restrict__ bsum,
                                                    int* __restrict__ cursor)
{
    int gid = blockIdx.x * 256 + threadIdx.x;
    if (gid < N_NODES) {
        int v = row_start[gid] + bsum[blockIdx.x];
        row_start[gid] = v;
        cursor[gid] = v;
    }
}

__global__ __launch_bounds__(256) void fill_kernel(const int* __restrict__ ei,
                                                   int* __restrict__ cursor,
                                                   int* __restrict__ csr_src)
{
    int e = blockIdx.x * 256 + threadIdx.x;
    if (e >= N_EDGES) return;
    int d = ei[N_EDGES + e];
    int pos = atomicAdd(&cursor[d], 1);
    csr_src[pos] = ei[e];
}

// ---------------- fused GIN layer -------------------------------------------
// per wave: [BN+ReLU folded reads] gather -> MLP1+ReLU -> MLP2 -> store+stats
// wave-autonomous: no __syncthreads in the main loop.
template<bool HASBN>
__global__ __launch_bounds__(512, 6) void layer_kernel(
    const float* __restrict__ hin, const int* __restrict__ csr_src,
    const int* __restrict__ row_start,
    const float* __restrict__ stats_prev, const float* __restrict__ gamma,
    const float* __restrict__ beta,
    const float* __restrict__ eps, int layer,
    const float* __restrict__ w1, const float* __restrict__ b1,
    const float* __restrict__ w2, const float* __restrict__ b2,
    float* __restrict__ hout, float* __restrict__ stats_cur)
{
    __shared__ __align__(16) float wT1[HIDDEN * PITCH];        // 17.4 KB
    __shared__ __align__(16) float wT2[HIDDEN * PITCH];        // 17.4 KB
    __shared__ __align__(16) float zb[LWAVES][4][HIDDEN];      // 8 KB, wave-private
    for (int i = threadIdx.x; i < HIDDEN * HIDDEN; i += 512) {
        int k = i >> 6, c = i & 63;
        wT1[c * PITCH + k] = w1[i];
        wT2[c * PITCH + k] = w2[i];
    }
    const int col = threadIdx.x & 63;
    const int wv  = threadIdx.x >> 6;
    float A = 1.0f, Bc = 0.0f;
    if (HASBN) {
        const float invN = 1.0f / (float)N_NODES;
        float mean = stats_prev[col] * invN;
        float var  = stats_prev[HIDDEN + col] * invN - mean * mean;
        float inv  = rsqrtf(fmaxf(var, 0.f) + BN_EPS);
        A = inv * gamma[col];
        Bc = beta[col] - mean * A;
    }
    const float sf  = 1.0f + eps[layer];
    const float b1c = b1[col], b2c = b2[col];
    __syncthreads();

    float s = 0.f, s2 = 0.f;
    const int nwaves = gridDim.x * LWAVES;
    for (int grp = blockIdx.x * LWAVES + wv; grp < N_NODES / 4; grp += nwaves) {
        const int nbase = grp * 4;
        // ---- gather 4 nodes into wave-private LDS slot ----
        for (int n = 0; n < 4; ++n) {
            const int node = nbase + n;
            const int s0 = row_start[node];
            const int s1 = row_start[node + 1];
            float v = hin[(size_t)node * HIDDEN + col];
            if (HASBN) v = fmaxf(fmaf(v, A, Bc), 0.f);
            float a0 = sf * v, a1 = 0.f, a2 = 0.f, a3 = 0.f;
            for (int jb = s0; jb < s1; jb += 64) {
                int m = s1 - jb; if (m > 64) m = 64;
                int idx = csr_src[jb + (col < m ? col : m - 1)];  // 1 coalesced load
                int j = 0;
                for (; j + 4 <= m; j += 4) {
                    int i0 = __shfl(idx, j + 0), i1 = __shfl(idx, j + 1);
                    int i2 = __shfl(idx, j + 2), i3 = __shfl(idx, j + 3);
                    float u0 = hin[(size_t)i0 * HIDDEN + col];
                    float u1 = hin[(size_t)i1 * HIDDEN + col];
                    float u2 = hin[(size_t)i2 * HIDDEN + col];
                    float u3 = hin[(size_t)i3 * HIDDEN + col];
                    if (HASBN) {
                        u0 = fmaxf(fmaf(u0, A, Bc), 0.f);
                        u1 = fmaxf(fmaf(u1, A, Bc), 0.f);
                        u2 = fmaxf(fmaf(u2, A, Bc), 0.f);
                        u3 = fmaxf(fmaf(u3, A, Bc), 0.f);
                    }
                    a0 += u0; a1 += u1; a2 += u2; a3 += u3;
                }
                for (; j < m; ++j) {
                    int i0 = __shfl(idx, j);
                    float u = hin[(size_t)i0 * HIDDEN + col];
                    if (HASBN) u = fmaxf(fmaf(u, A, Bc), 0.f);
                    a0 += u;
                }
            }
            zb[wv][n][col] = (a0 + a1) + (a2 + a3);
        }
        // ---- MLP1: o = relu(z @ w1 + b1) (wave-private LDS, no barrier) ----
        float o0 = b1c, o1 = b1c, o2 = b1c, o3 = b1c;
        #pragma unroll 4
        for (int kc = 0; kc < HIDDEN / 4; ++kc) {
            float4 w4 = *(const float4*)&wT1[col * PITCH + 4 * kc];
            float4 z0 = *(const float4*)&zb[wv][0][4 * kc];
            float4 z1 = *(const float4*)&zb[wv][1][4 * kc];
            float4 z2 = *(const float4*)&zb[wv][2][4 * kc];
            float4 z3 = *(const float4*)&zb[wv][3][4 * kc];
            o0 = fmaf(w4.x, z0.x, fmaf(w4.y, z0.y, fmaf(w4.z, z0.z, fmaf(w4.w, z0.w, o0))));
            o1 = fmaf(w4.x, z1.x, fmaf(w4.y, z1.y, fmaf(w4.z, z1.z, fmaf(w4.w, z1.w, o1))));
            o2 = fmaf(w4.x, z2.x, fmaf(w4.y, z2.y, fmaf(w4.z, z2.z, fmaf(w4.w, z2.w, o2))));
            o3 = fmaf(w4.x, z3.x, fmaf(w4.y, z3.y, fmaf(w4.z, z3.z, fmaf(w4.w, z3.w, o3))));
        }
        zb[wv][0][col] = fmaxf(o0, 0.f);
        zb[wv][1][col] = fmaxf(o1, 0.f);
        zb[wv][2][col] = fmaxf(o2, 0.f);
        zb[wv][3][col] = fmaxf(o3, 0.f);
        // ---- MLP2: p = y @ w2 + b2 ----
        float p0 = b2c, p1 = b2c, p2 = b2c, p3 = b2c;
        #pragma unroll 4
        for (int kc = 0; kc < HIDDEN / 4; ++kc) {
            float4 w4 = *(const float4*)&wT2[col * PITCH + 4 * kc];
            float4 z0 = *(const float4*)&zb[wv][0][4 * kc];
            float4 z1 = *(const float4*)&zb[wv][1][4 * kc];
            float4 z2 = *(const float4*)&zb[wv][2][4 * kc];
            float4 z3 = *(const float4*)&zb[wv][3][4 * kc];
            p0 = fmaf(w4.x, z0.x, fmaf(w4.y, z0.y, fmaf(w4.z, z0.z, fmaf(w4.w, z0.w, p0))));
            p1 = fmaf(w4.x, z1.x, fmaf(w4.y, z1.y, fmaf(w4.z, z1.z, fmaf(w4.w, z1.w, p1))));
            p2 = fmaf(w4.x, z2.x, fmaf(w4.y, z2.y, fmaf(w4.z, z2.z, fmaf(w4.w, z2.w, p2))));
            p3 = fmaf(w4.x, z3.x, fmaf(w4.y, z3.y, fmaf(w4.z, z3.z, fmaf(w4.w, z3.w, p3))));
        }
        hout[(size_t)(nbase + 0) * HIDDEN + col] = p0;
        hout[(size_t)(nbase + 1) * HIDDEN + col] = p1;
        hout[(size_t)(nbase + 2) * HIDDEN + col] = p2;
        hout[(size_t)(nbase + 3) * HIDDEN + col] = p3;
        s  += ((p0 + p1) + (p2 + p3));
        s2 += ((p0 * p0 + p1 * p1) + (p2 * p2 + p3 * p3));
    }
    // ---- block-level BN-stats reduction (reuse zb as scratch: 2x512 floats) ----
    __syncthreads();
    float* red = &zb[0][0][0];
    red[threadIdx.x] = s;
    red[512 + threadIdx.x] = s2;
    __syncthreads();
    if (wv == 0) {
        float ts = 0.f, ts2 = 0.f;
        #pragma unroll
        for (int wq = 0; wq < LWAVES; ++wq) {
            ts  += red[wq * 64 + col];
            ts2 += red[512 + wq * 64 + col];
        }
        atomicAdd(&stats_cur[col], ts);
        atomicAdd(&stats_cur[HIDDEN + col], ts2);
    }
}

__device__ __forceinline__ int lbound(const int* __restrict__ a, int n, int v)
{
    int lo = 0, hi = n;
    while (lo < hi) { int m = (lo + hi) >> 1; if (a[m] < v) lo = m + 1; else hi = m; }
    return lo;
}

// ---------------- mean pool per graph, BN+ReLU of last layer folded in ----
__global__ __launch_bounds__(256) void pool_kernel(
    const float* __restrict__ hpre, const int* __restrict__ batch,
    const float* __restrict__ stats, const float* __restrict__ gamma,
    const float* __restrict__ beta, float* __restrict__ pooled)
{
    __shared__ int bounds[2];
    __shared__ float red[256];
    const int g = blockIdx.x;
    if (threadIdx.x < 2)
        bounds[threadIdx.x] = lbound(batch, N_NODES, g + threadIdx.x);
    __syncthreads();
    const int start = bounds[0], end = bounds[1];
    const int col = threadIdx.x & 63;
    const int row = threadIdx.x >> 6;
    const float invN = 1.0f / (float)N_NODES;
    float mean = stats[col] * invN;
    float var  = stats[HIDDEN + col] * invN - mean * mean;
    float inv  = rsqrtf(fmaxf(var, 0.f) + BN_EPS);
    float A = inv * gamma[col];
    float B = beta[col] - mean * A;
    float s = 0.f;
    for (int r = start + row; r < end; r += 4)
        s += fmaxf(fmaf(hpre[(size_t)r * HIDDEN + col], A, B), 0.f);
    red[threadIdx.x] = s;
    __syncthreads();
    if (row == 0) {
        float t = red[col] + red[64 + col] + red[128 + col] + red[192 + col];
        pooled[(size_t)g * HIDDEN + col] = t / fmaxf((float)(end - start), 1.0f);
    }
}

// ---------------- out = pooled @ lin_w + lin_b ------------------------------
__global__ void out_kernel(const float* __restrict__ pooled,
                           const float* __restrict__ w, const float* __restrict__ b,
                           float* __restrict__ out)
{
    int gid = blockIdx.x * blockDim.x + threadIdx.x;
    if (gid >= N_GRAPHS * N_CLASSES) return;
    int g = gid / N_CLASSES;
    int c = gid - g * N_CLASSES;
    float acc = b[c];
    for (int j = 0; j < HIDDEN; ++j)
        acc = fmaf(pooled[(size_t)g * HIDDEN + j], w[j * N_CLASSES + c], acc);
    out[gid] = acc;
}

extern "C" void kernel_launch(void* const* d_in, const int* in_sizes, int n_in,
                              void* d_out, int out_size, void* d_ws, size_t ws_size,
                              hipStream_t stream)
{
    const float* x       = (const float*)d_in[0];
    const int*   ei      = (const int*)d_in[1];   // [2, N_EDGES]: src then dst
    const int*   batch   = (const int*)d_in[2];
    const float* enc_w   = (const float*)d_in[3];
    const float* enc_b   = (const float*)d_in[4];
    const float* eps     = (const float*)d_in[5];
    const float* conv_w1 = (const float*)d_in[6];
    const float* conv_b1 = (const float*)d_in[7];
    const float* conv_w2 = (const float*)d_in[8];
    const float* conv_b2 = (const float*)d_in[9];
    const float* bn_g    = (const float*)d_in[10];
    const float* bn_b    = (const float*)d_in[11];
    const float* lin_w   = (const float*)d_in[12];
    const float* lin_b   = (const float*)d_in[13];
    float* out = (float*)d_out;

    char* ws = (char*)d_ws;
    const size_t HB = (size_t)N_NODES * HIDDEN * sizeof(float);  // 12.8 MB
    size_t off = 0;
    float* P      = (float*)(ws + off); off += HB;          // ping
    float* Q      = (float*)(ws + off); off += HB;          // pong
    float* stats  = (float*)(ws + off); off += N_LAYERS * 2 * HIDDEN * sizeof(float);
    float* pooled = (float*)(ws + off); off += (size_t)N_GRAPHS * HIDDEN * sizeof(float);
    int* deg       = (int*)(ws + off); off += 50176 * sizeof(int);
    int* row_start = (int*)(ws + off); off += 50176 * sizeof(int);   // N_NODES+1 used
    int* cursor    = (int*)(ws + off); off += 50176 * sizeof(int);
    int* bsum      = (int*)(ws + off); off += 256 * sizeof(int);
    int* csr_src   = (int*)(ws + off); off += (size_t)N_EDGES * sizeof(int);

    hipMemsetAsync(deg, 0, N_NODES * sizeof(int), stream);
    hipMemsetAsync(stats, 0, N_LAYERS * 2 * HIDDEN * sizeof(float), stream);

    enc_kernel<<<768, 512, 0, stream>>>(x, enc_w, enc_b, P);

    hist_kernel<<<(N_EDGES + 255) / 256, 256, 0, stream>>>(ei, deg);
    scan1_kernel<<<SCAN_BLK, 256, 0, stream>>>(deg, row_start, bsum);
    scan2_kernel<<<1, 256, 0, stream>>>(bsum, row_start);
    scan3_kernel<<<SCAN_BLK, 256, 0, stream>>>(row_start, bsum, cursor);
    fill_kernel<<<(N_EDGES + 255) / 256, 256, 0, stream>>>(ei, cursor, csr_src);

    const float* curin = P;
    float* curout = Q;
    for (int l = 0; l < N_LAYERS; ++l) {
        const float* w1 = conv_w1 + (size_t)l * HIDDEN * HIDDEN;
        const float* b1 = conv_b1 + (size_t)l * HIDDEN;
        const float* w2 = conv_w2 + (size_t)l * HIDDEN * HIDDEN;
        const float* b2 = conv_b2 + (size_t)l * HIDDEN;
        if (l == 0)
            layer_kernel<false><<<768, 512, 0, stream>>>(
                curin, csr_src, row_start, nullptr, nullptr, nullptr,
                eps, l, w1, b1, w2, b2, curout, stats);
        else
            layer_kernel<true><<<768, 512, 0, stream>>>(
                curin, csr_src, row_start,
                stats + (size_t)(l - 1) * 2 * HIDDEN,
                bn_g + (size_t)(l - 1) * HIDDEN, bn_b + (size_t)(l - 1) * HIDDEN,
                eps, l, w1, b1, w2, b2, curout, stats + (size_t)l * 2 * HIDDEN);
        const float* t = curout; curout = (float*)curin; curin = t;
    }
    // after 3 layers: final pre-BN activations are in Q (P->Q->P->Q)

    pool_kernel<<<N_GRAPHS, 256, 0, stream>>>(
        Q, batch, stats + (size_t)(N_LAYERS - 1) * 2 * HIDDEN,
        bn_g + (size_t)(N_LAYERS - 1) * HIDDEN, bn_b + (size_t)(N_LAYERS - 1) * HIDDEN,
        pooled);
    out_kernel<<<(N_GRAPHS * N_CLASSES + 255) / 256, 256, 0, stream>>>(pooled, lin_w, lin_b, out);
}